// Round 10
// baseline (64.265 us; speedup 1.0000x reference)
//
#include <hip/hip_runtime.h>
#include <math.h>

#define NROWS 4096
#define DDIM  64
#define NBINS 2048
#define HIST_W    0.25f    // 2048 bins over [0, 512)
#define HIST_INVW 4.0f

// ws layout (bytes):
// [0       .. 8192   )  hist (2048 u32)           -- zeroed by prep each call
// [8192    .. 24576  )  x_sq (4096 f32)
// [24576   .. 40960  )  y_sq (4096 f32)
// [40960   .. 40976  )  params[0] = c = -gamma*log2(e); +8: done counter
// [65536   .. 2162688)  Xh, Xl, Yh, Yl (each 4096x64 bf16 = 512 KB)
// [2359296 .. +1MB   )  partial[128][2048] u32
//
// Fragment-major bf16 layout: (row,k) -> ((row>>4)*8 + (k>>3))*128 + (row&15)*8 + (k&7)
// => one MFMA fragment (16 rows x 32 k) = base + lane*8 shorts (coalesced 1 KB wave load).

typedef __attribute__((ext_vector_type(8))) short short8;
typedef __attribute__((ext_vector_type(4))) float f32x4;

__device__ inline unsigned short f2bf(float f) {           // RNE f32 -> bf16 bits
    unsigned u = __builtin_bit_cast(unsigned, f);
    u += 0x7FFFu + ((u >> 16) & 1u);
    return (unsigned short)(u >> 16);
}
__device__ inline float bf2f(unsigned short h) {
    unsigned u = ((unsigned)h) << 16;
    return __builtin_bit_cast(float, u);
}

__global__ void prep_kernel(const float* __restrict__ X, const float* __restrict__ Y,
                            unsigned short* __restrict__ Xh, unsigned short* __restrict__ Xl,
                            unsigned short* __restrict__ Yh, unsigned short* __restrict__ Yl,
                            float* __restrict__ x_sq, float* __restrict__ y_sq,
                            unsigned* __restrict__ hist, unsigned* __restrict__ done) {
    int gid = blockIdx.x * blockDim.x + threadIdx.x;       // 0..65535
    if (gid < NBINS) hist[gid] = 0u;
    if (gid == 0) *done = 0u;
    int row = gid >> 3, kb = gid & 7;                      // one row-octet per thread
    int r = (row < NROWS) ? row : row - NROWS;
    const float* src = ((row < NROWS) ? X : Y) + (size_t)r * DDIM + kb * 8;
    unsigned short* dh = (row < NROWS) ? Xh : Yh;
    unsigned short* dl = (row < NROWS) ? Xl : Yl;
    float* sq = (row < NROWS) ? x_sq : y_sq;

    float4 a = *(const float4*)src;
    float4 b = *(const float4*)(src + 4);
    float v[8] = {a.x, a.y, a.z, a.w, b.x, b.y, b.z, b.w};
    short8 vh, vl;
    float s = 0.f;
#pragma unroll
    for (int j = 0; j < 8; ++j) {
        s = fmaf(v[j], v[j], s);
        unsigned short h = f2bf(v[j]);
        vh[j] = (short)h;
        vl[j] = (short)f2bf(v[j] - bf2f(h));
    }
    s += __shfl_xor(s, 1);
    s += __shfl_xor(s, 2);
    s += __shfl_xor(s, 4);
    if (kb == 0) sq[r] = s;
    size_t o = ((size_t)(r >> 4) * 8 + kb) * 128 + (size_t)(r & 15) * 8;
    *(short8*)(dh + o) = vh;
    *(short8*)(dl + o) = vl;
}

// computes one wave's 64x64 acc tile at (i0, j0).
// FULL:  4-term split-bf16 (exact to ~1e-3); !FULL: Xh*Yh only (median binning).
// SWAP:  operands exchanged -> D-col = lane&15 = X-row, D-row = (lane>>4)*4+q = Y-col
//        (acc[r][c] holds 4 CONTIGUOUS output columns -> direct f32x4 stores).
template <bool FULL, bool SWAP, typename F>
__device__ inline void compute_tile(const unsigned short* __restrict__ Xh, const unsigned short* __restrict__ Xl,
                                    const unsigned short* __restrict__ Yh, const unsigned short* __restrict__ Yl,
                                    int i0, int j0, size_t la, F&& body) {
    const int pa0 = i0 >> 4, pb0 = j0 >> 4;
    f32x4 acc[4][4];
#pragma unroll
    for (int r = 0; r < 4; ++r)
#pragma unroll
        for (int c = 0; c < 4; ++c) acc[r][c] = (f32x4){0.f, 0.f, 0.f, 0.f};

    auto step = [&](const unsigned short* A, const unsigned short* B, int kh) {
        short8 af[4], bg[4];
#pragma unroll
        for (int g = 0; g < 4; ++g) {
            af[g] = *(const short8*)(A + ((size_t)(pa0 + g) * 8 + kh * 4) * 128 + la);
            bg[g] = *(const short8*)(B + ((size_t)(pb0 + g) * 8 + kh * 4) * 128 + la);
        }
#pragma unroll
        for (int r = 0; r < 4; ++r)
#pragma unroll
            for (int c = 0; c < 4; ++c)
                acc[r][c] = SWAP
                    ? __builtin_amdgcn_mfma_f32_16x16x32_bf16(bg[c], af[r], acc[r][c], 0, 0, 0)
                    : __builtin_amdgcn_mfma_f32_16x16x32_bf16(af[r], bg[c], acc[r][c], 0, 0, 0);
    };
    step(Xh, Yh, 0); step(Xh, Yh, 1);
    if (FULL) {
        step(Xl, Yh, 0); step(Xl, Yh, 1);
        step(Xh, Yl, 0); step(Xh, Yl, 1);
        step(Xl, Yl, 0); step(Xl, Yl, 1);
    }
    body(acc);
}

// Histogram pass: 128 blocks (4x32); each block does ONE 128x128 tile with a
// rotating column offset so every row and column is sampled 512x (1/8 of the
// matrix, 2.1M samples). Xh*Yh only. LDS-binned, one contiguous 8KB partial
// write per block (no global atomics).
__launch_bounds__(256, 2)
__global__ void hist_kernel(const unsigned short* __restrict__ Xh, const unsigned short* __restrict__ Xl,
                            const unsigned short* __restrict__ Yh, const unsigned short* __restrict__ Yl,
                            const float* __restrict__ x_sq, const float* __restrict__ y_sq,
                            unsigned* __restrict__ partial) {
    __shared__ unsigned lhist[NBINS];
    const int t    = threadIdx.x;
    const int wave = t >> 6;
    const int lane = t & 63;
    const int fr = lane & 15;
    const int rb = (lane >> 4) * 4;
    const size_t la = (size_t)lane * 8;
    const int i0 = blockIdx.y * 128 + (wave >> 1) * 64;
    const int j0 = blockIdx.x * 1024 + (blockIdx.y & 7) * 128 + (wave & 1) * 64;

#pragma unroll
    for (int i = 0; i < NBINS / 256; ++i) lhist[t + i * 256] = 0u;
    __syncthreads();

    float xsv[4][4];
#pragma unroll
    for (int r = 0; r < 4; ++r)
#pragma unroll
        for (int q = 0; q < 4; ++q) xsv[r][q] = x_sq[i0 + r * 16 + rb + q];
    float ysv[4];
#pragma unroll
    for (int c = 0; c < 4; ++c) ysv[c] = y_sq[j0 + c * 16 + fr];

    compute_tile<false, false>(Xh, Xl, Yh, Yl, i0, j0, la, [&](f32x4 (&acc)[4][4]) {
#pragma unroll
        for (int r = 0; r < 4; ++r)
#pragma unroll
            for (int q = 0; q < 4; ++q) {
                float xs = xsv[r][q];
#pragma unroll
                for (int c = 0; c < 4; ++c) {
                    float dv = fmaf(-2.f, acc[r][c][q], xs + ysv[c]);
                    int idx = (int)(dv * HIST_INVW);
                    idx = idx < 0 ? 0 : (idx > NBINS - 1 ? NBINS - 1 : idx);
                    atomicAdd(&lhist[idx], 1u);
                }
            }
    });
    __syncthreads();
    unsigned* dst = partial + (size_t)(blockIdx.y * gridDim.x + blockIdx.x) * NBINS;
#pragma unroll
    for (int i = 0; i < NBINS / 256; ++i) dst[t + i * 256] = lhist[t + i * 256];
}

// Sum partial[128][2048] -> hist[2048] (64 blocks), then the LAST finishing
// block computes the median + params (canonical threadfence/done pattern).
__global__ void reduce_scan_kernel(const unsigned* __restrict__ partial, unsigned* __restrict__ hist,
                                   unsigned* __restrict__ done, float* __restrict__ params) {
    __shared__ unsigned cnt[NBINS];
    __shared__ unsigned tsum[256];
    __shared__ float vmed[2];
    __shared__ int is_last;
    const int t = threadIdx.x;

    {   // reduce part: gid covers 2048 bins x 8 slices of 16 partial rows
        int gid = blockIdx.x * 256 + t;          // 0..16383
        int bin = gid & (NBINS - 1);
        int sl  = gid >> 11;                     // 0..7
        const unsigned* p = partial + (size_t)sl * 16 * NBINS + bin;
        unsigned s = 0;
#pragma unroll 8
        for (int i = 0; i < 16; ++i) s += p[(size_t)i * NBINS];
        atomicAdd(&hist[bin], s);
    }
    __threadfence();
    __syncthreads();
    if (t == 0) is_last = (atomicAdd(done, 1u) == 63u);
    __syncthreads();
    if (!is_last) return;

    // scan part (runs in exactly one block, after all hist adds are visible).
    // Read hist via atomic RMW (L1-bypass) to avoid stale-cache reads.
    unsigned s = 0;
#pragma unroll
    for (int i = 0; i < NBINS / 256; ++i) {
        unsigned cv = atomicAdd(&hist[t * (NBINS / 256) + i], 0u);
        cnt[t * (NBINS / 256) + i] = cv;
        s += cv;
    }
    tsum[t] = s;
    __syncthreads();
    for (int off = 1; off < 256; off <<= 1) {
        unsigned v = (t >= off) ? tsum[t - off] : 0u;
        __syncthreads();
        tsum[t] += v;
        __syncthreads();
    }
    unsigned cum = (t == 0) ? 0u : tsum[t - 1];
    unsigned total = tsum[255];
    // torch median ranks (0-based): even -> avg of total/2-1, total/2; odd -> (total-1)/2
    const unsigned K2 = total >> 1;
    const unsigned K1 = K2 - 1u + (total & 1u);

    for (int i = 0; i < NBINS / 256; ++i) {
        int b = t * (NBINS / 256) + i;
        unsigned cv = cnt[b];
        if (cv) {
            if (K1 >= cum && (K1 - cum) < cv) {
                float frac = ((float)(K1 - cum) + 0.5f) / (float)cv;
                vmed[0] = ((float)b + frac) * HIST_W;
            }
            if (K2 >= cum && (K2 - cum) < cv) {
                float frac = ((float)(K2 - cum) + 0.5f) / (float)cv;
                vmed[1] = ((float)b + frac) * HIST_W;
            }
        }
        cum += cv;
    }
    __syncthreads();
    if (t == 0) {
        double med   = 0.5 * ((double)vmed[0] + (double)vmed[1]);
        double gamma = 8.317766166719343 / med;               // ln(4096) / med
        params[0] = (float)(-gamma * 1.4426950408889634);     // -gamma * log2(e)
    }
}

// Exp-write pass, operand-swapped MFMA: each lane's acc f32x4 is 4 CONTIGUOUS
// output columns -> direct 16B stores (64B segments per 4 lanes), no LDS.
__launch_bounds__(256, 4)
__global__ void write_kernel(const unsigned short* __restrict__ Xh, const unsigned short* __restrict__ Xl,
                             const unsigned short* __restrict__ Yh, const unsigned short* __restrict__ Yl,
                             const float* __restrict__ x_sq, const float* __restrict__ y_sq,
                             const float* __restrict__ params, float* __restrict__ out) {
    const int t    = threadIdx.x;
    const int wave = t >> 6;
    const int lane = t & 63;
    const int fr = lane & 15;
    const int rb = (lane >> 4) * 4;
    const size_t la = (size_t)lane * 8;
    const int i0 = blockIdx.y * 128 + (wave >> 1) * 64;
    const int j0 = blockIdx.x * 128 + (wave & 1) * 64;
    const float cc = params[0];

    float xsv[4];
#pragma unroll
    for (int r = 0; r < 4; ++r) xsv[r] = x_sq[i0 + r * 16 + fr];
    f32x4 ysq4[4];
#pragma unroll
    for (int c = 0; c < 4; ++c) ysq4[c] = *(const f32x4*)&y_sq[j0 + c * 16 + rb];

    compute_tile<true, true>(Xh, Xl, Yh, Yl, i0, j0, la, [&](f32x4 (&acc)[4][4]) {
#pragma unroll
        for (int r = 0; r < 4; ++r) {
            const int row = i0 + r * 16 + fr;
            const float xs = xsv[r];
#pragma unroll
            for (int c = 0; c < 4; ++c) {
                f32x4 v;
#pragma unroll
                for (int q = 0; q < 4; ++q) {
                    float dv = fmaf(-2.f, acc[r][c][q], xs + ysq4[c][q]);
                    v[q] = __builtin_amdgcn_exp2f(cc * dv);
                }
                f32x4* po = (f32x4*)(out + (size_t)row * NROWS + j0 + c * 16 + rb);
                __builtin_nontemporal_store(v, po);
            }
        }
    });
}

extern "C" void kernel_launch(void* const* d_in, const int* in_sizes, int n_in,
                              void* d_out, int out_size, void* d_ws, size_t ws_size,
                              hipStream_t stream) {
    const float* X = (const float*)d_in[0];
    const float* Y = (const float*)d_in[1];
    float* out = (float*)d_out;

    unsigned* hist     = (unsigned*)d_ws;
    float* x_sq        = (float*)((char*)d_ws + 8192);
    float* y_sq        = (float*)((char*)d_ws + 24576);
    float* params      = (float*)((char*)d_ws + 40960);
    unsigned* done     = (unsigned*)((char*)d_ws + 40968);
    unsigned short* Xh = (unsigned short*)((char*)d_ws + 65536);
    unsigned short* Xl = Xh + (size_t)NROWS * DDIM;
    unsigned short* Yh = Xl + (size_t)NROWS * DDIM;
    unsigned short* Yl = Yh + (size_t)NROWS * DDIM;
    unsigned* partial  = (unsigned*)((char*)d_ws + 2359296);   // 1 MB used

    prep_kernel<<<256, 256, 0, stream>>>(X, Y, Xh, Xl, Yh, Yl, x_sq, y_sq, hist, done);
    hist_kernel<<<dim3(4, 32), 256, 0, stream>>>(Xh, Xl, Yh, Yl, x_sq, y_sq, partial);
    reduce_scan_kernel<<<64, 256, 0, stream>>>(partial, hist, done, params);
    write_kernel<<<dim3(32, 32), 256, 0, stream>>>(Xh, Xl, Yh, Yl, x_sq, y_sq, params, out);
}

// Round 11
// 41.135 us; speedup vs baseline: 1.5623x; 1.5623x over previous
//
#include <hip/hip_runtime.h>
#include <math.h>

#define NROWS 4096
#define DDIM  64
#define NBINS 2048
#define HIST_W    0.25f    // 2048 bins over [0, 512)
#define HIST_INVW 4.0f

// ws layout (bytes):
// [0       .. 8192   )  hist (2048 u32)           -- zeroed by prep each call
// [8192    .. 24576  )  x_sq (4096 f32)
// [24576   .. 40960  )  y_sq (4096 f32)
// [40960   .. 40976  )  params[0] = c = -gamma*log2(e); +8: done counter
// [65536   .. 2162688)  Xh, Xl, Yh, Yl (each 4096x64 bf16 = 512 KB)
// [2359296 .. +1MB   )  partial[128][2048] u32
//
// Fragment-major bf16 layout: (row,k) -> ((row>>4)*8 + (k>>3))*128 + (row&15)*8 + (k&7)
// => one MFMA fragment (16 rows x 32 k) = base + lane*8 shorts (coalesced 1 KB wave load).
//
// HW lesson (R4/R10 vs R6): wave stores must cover full 128B lines per
// instruction (e.g. 64 lanes x 16B contiguous). Partial-line segments (even
// 64B) amplify HBM writes ~2x. Hence the LDS-transpose epilogue in write.

typedef __attribute__((ext_vector_type(8))) short short8;
typedef __attribute__((ext_vector_type(4))) float f32x4;

__device__ inline unsigned short f2bf(float f) {           // RNE f32 -> bf16 bits
    unsigned u = __builtin_bit_cast(unsigned, f);
    u += 0x7FFFu + ((u >> 16) & 1u);
    return (unsigned short)(u >> 16);
}
__device__ inline float bf2f(unsigned short h) {
    unsigned u = ((unsigned)h) << 16;
    return __builtin_bit_cast(float, u);
}

__global__ void prep_kernel(const float* __restrict__ X, const float* __restrict__ Y,
                            unsigned short* __restrict__ Xh, unsigned short* __restrict__ Xl,
                            unsigned short* __restrict__ Yh, unsigned short* __restrict__ Yl,
                            float* __restrict__ x_sq, float* __restrict__ y_sq,
                            unsigned* __restrict__ hist, unsigned* __restrict__ done) {
    int gid = blockIdx.x * blockDim.x + threadIdx.x;       // 0..65535
    if (gid < NBINS) hist[gid] = 0u;
    if (gid == 0) *done = 0u;
    int row = gid >> 3, kb = gid & 7;                      // one row-octet per thread
    int r = (row < NROWS) ? row : row - NROWS;
    const float* src = ((row < NROWS) ? X : Y) + (size_t)r * DDIM + kb * 8;
    unsigned short* dh = (row < NROWS) ? Xh : Yh;
    unsigned short* dl = (row < NROWS) ? Xl : Yl;
    float* sq = (row < NROWS) ? x_sq : y_sq;

    float4 a = *(const float4*)src;
    float4 b = *(const float4*)(src + 4);
    float v[8] = {a.x, a.y, a.z, a.w, b.x, b.y, b.z, b.w};
    short8 vh, vl;
    float s = 0.f;
#pragma unroll
    for (int j = 0; j < 8; ++j) {
        s = fmaf(v[j], v[j], s);
        unsigned short h = f2bf(v[j]);
        vh[j] = (short)h;
        vl[j] = (short)f2bf(v[j] - bf2f(h));
    }
    s += __shfl_xor(s, 1);
    s += __shfl_xor(s, 2);
    s += __shfl_xor(s, 4);
    if (kb == 0) sq[r] = s;
    size_t o = ((size_t)(r >> 4) * 8 + kb) * 128 + (size_t)(r & 15) * 8;
    *(short8*)(dh + o) = vh;
    *(short8*)(dl + o) = vl;
}

// computes one wave's 64x64 acc tile of X*Y' at (i0, j0).
// FULL: 4-term split-bf16 (exact to ~1e-3). !FULL: Xh*Yh only (d error ~0.03,
// fine for median binning at 0.25 bin width).
template <bool FULL, typename F>
__device__ inline void compute_tile(const unsigned short* __restrict__ Xh, const unsigned short* __restrict__ Xl,
                                    const unsigned short* __restrict__ Yh, const unsigned short* __restrict__ Yl,
                                    int i0, int j0, size_t la, F&& body) {
    const int pa0 = i0 >> 4, pb0 = j0 >> 4;
    f32x4 acc[4][4];
#pragma unroll
    for (int r = 0; r < 4; ++r)
#pragma unroll
        for (int c = 0; c < 4; ++c) acc[r][c] = (f32x4){0.f, 0.f, 0.f, 0.f};

    auto step = [&](const unsigned short* A, const unsigned short* B, int kh) {
        short8 af[4], bg[4];
#pragma unroll
        for (int g = 0; g < 4; ++g) {
            af[g] = *(const short8*)(A + ((size_t)(pa0 + g) * 8 + kh * 4) * 128 + la);
            bg[g] = *(const short8*)(B + ((size_t)(pb0 + g) * 8 + kh * 4) * 128 + la);
        }
#pragma unroll
        for (int r = 0; r < 4; ++r)
#pragma unroll
            for (int c = 0; c < 4; ++c)
                acc[r][c] = __builtin_amdgcn_mfma_f32_16x16x32_bf16(af[r], bg[c], acc[r][c], 0, 0, 0);
    };
    step(Xh, Yh, 0); step(Xh, Yh, 1);
    if (FULL) {
        step(Xl, Yh, 0); step(Xl, Yh, 1);
        step(Xh, Yl, 0); step(Xh, Yl, 1);
        step(Xl, Yl, 0); step(Xl, Yl, 1);
    }
    body(acc);
}

// Histogram pass: 128 blocks (4x32); each block does ONE 128x128 tile with a
// rotating column offset so every row and column is sampled 512x (1/8 of the
// matrix, 2.1M samples). Xh*Yh only. LDS-binned, one contiguous 8KB partial
// write per block (no global atomics).
__launch_bounds__(256, 2)
__global__ void hist_kernel(const unsigned short* __restrict__ Xh, const unsigned short* __restrict__ Xl,
                            const unsigned short* __restrict__ Yh, const unsigned short* __restrict__ Yl,
                            const float* __restrict__ x_sq, const float* __restrict__ y_sq,
                            unsigned* __restrict__ partial) {
    __shared__ unsigned lhist[NBINS];
    const int t    = threadIdx.x;
    const int wave = t >> 6;
    const int lane = t & 63;
    const int fr = lane & 15;
    const int rb = (lane >> 4) * 4;
    const size_t la = (size_t)lane * 8;
    const int i0 = blockIdx.y * 128 + (wave >> 1) * 64;
    const int j0 = blockIdx.x * 1024 + (blockIdx.y & 7) * 128 + (wave & 1) * 64;

#pragma unroll
    for (int i = 0; i < NBINS / 256; ++i) lhist[t + i * 256] = 0u;
    __syncthreads();

    float xsv[4][4];
#pragma unroll
    for (int r = 0; r < 4; ++r)
#pragma unroll
        for (int q = 0; q < 4; ++q) xsv[r][q] = x_sq[i0 + r * 16 + rb + q];
    float ysv[4];
#pragma unroll
    for (int c = 0; c < 4; ++c) ysv[c] = y_sq[j0 + c * 16 + fr];

    compute_tile<false>(Xh, Xl, Yh, Yl, i0, j0, la, [&](f32x4 (&acc)[4][4]) {
#pragma unroll
        for (int r = 0; r < 4; ++r)
#pragma unroll
            for (int q = 0; q < 4; ++q) {
                float xs = xsv[r][q];
#pragma unroll
                for (int c = 0; c < 4; ++c) {
                    float dv = fmaf(-2.f, acc[r][c][q], xs + ysv[c]);
                    int idx = (int)(dv * HIST_INVW);
                    idx = idx < 0 ? 0 : (idx > NBINS - 1 ? NBINS - 1 : idx);
                    atomicAdd(&lhist[idx], 1u);
                }
            }
    });
    __syncthreads();
    unsigned* dst = partial + (size_t)(blockIdx.y * gridDim.x + blockIdx.x) * NBINS;
#pragma unroll
    for (int i = 0; i < NBINS / 256; ++i) dst[t + i * 256] = lhist[t + i * 256];
}

// Sum partial[128][2048] -> hist[2048] (64 blocks), then the LAST finishing
// block computes the median + params (canonical threadfence/done pattern).
__global__ void reduce_scan_kernel(const unsigned* __restrict__ partial, unsigned* __restrict__ hist,
                                   unsigned* __restrict__ done, float* __restrict__ params) {
    __shared__ unsigned cnt[NBINS];
    __shared__ unsigned tsum[256];
    __shared__ float vmed[2];
    __shared__ int is_last;
    const int t = threadIdx.x;

    {   // reduce part: gid covers 2048 bins x 8 slices of 16 partial rows
        int gid = blockIdx.x * 256 + t;          // 0..16383
        int bin = gid & (NBINS - 1);
        int sl  = gid >> 11;                     // 0..7
        const unsigned* p = partial + (size_t)sl * 16 * NBINS + bin;
        unsigned s = 0;
#pragma unroll 8
        for (int i = 0; i < 16; ++i) s += p[(size_t)i * NBINS];
        atomicAdd(&hist[bin], s);
    }
    __threadfence();
    __syncthreads();
    if (t == 0) is_last = (atomicAdd(done, 1u) == 63u);
    __syncthreads();
    if (!is_last) return;

    // scan part (runs in exactly one block, after all hist adds are visible).
    // Read hist via atomic RMW (L1-bypass) to avoid stale-cache reads.
    unsigned s = 0;
#pragma unroll
    for (int i = 0; i < NBINS / 256; ++i) {
        unsigned cv = atomicAdd(&hist[t * (NBINS / 256) + i], 0u);
        cnt[t * (NBINS / 256) + i] = cv;
        s += cv;
    }
    tsum[t] = s;
    __syncthreads();
    for (int off = 1; off < 256; off <<= 1) {
        unsigned v = (t >= off) ? tsum[t - off] : 0u;
        __syncthreads();
        tsum[t] += v;
        __syncthreads();
    }
    unsigned cum = (t == 0) ? 0u : tsum[t - 1];
    unsigned total = tsum[255];
    // torch median ranks (0-based): even -> avg of total/2-1, total/2; odd -> (total-1)/2
    const unsigned K2 = total >> 1;
    const unsigned K1 = K2 - 1u + (total & 1u);

    for (int i = 0; i < NBINS / 256; ++i) {
        int b = t * (NBINS / 256) + i;
        unsigned cv = cnt[b];
        if (cv) {
            if (K1 >= cum && (K1 - cum) < cv) {
                float frac = ((float)(K1 - cum) + 0.5f) / (float)cv;
                vmed[0] = ((float)b + frac) * HIST_W;
            }
            if (K2 >= cum && (K2 - cum) < cv) {
                float frac = ((float)(K2 - cum) + 0.5f) / (float)cv;
                vmed[1] = ((float)b + frac) * HIST_W;
            }
        }
        cum += cv;
    }
    __syncthreads();
    if (t == 0) {
        double med   = 0.5 * ((double)vmed[0] + (double)vmed[1]);
        double gamma = 8.317766166719343 / med;               // ln(4096) / med
        params[0] = (float)(-gamma * 1.4426950408889634);     // -gamma * log2(e)
    }
}

// Exp-write pass with full-tile LDS-transpose epilogue (verified fast, R6/R8):
// scatter all 64 rows, then 16 wave-stores each covering 1 KB contiguous
// (8 full 128B lines) — the only store shape that avoids write amplification.
__launch_bounds__(256, 2)
__global__ void write_kernel(const unsigned short* __restrict__ Xh, const unsigned short* __restrict__ Xl,
                             const unsigned short* __restrict__ Yh, const unsigned short* __restrict__ Yl,
                             const float* __restrict__ x_sq, const float* __restrict__ y_sq,
                             const float* __restrict__ params, float* __restrict__ out) {
    __shared__ float T[4][64][68];   // 69,632 B; per-wave private 64x64 tile, pad 68
    const int t    = threadIdx.x;
    const int wave = t >> 6;
    const int lane = t & 63;
    const int fr = lane & 15;
    const int rb = (lane >> 4) * 4;
    const size_t la = (size_t)lane * 8;
    const int i0 = blockIdx.y * 128 + (wave >> 1) * 64;
    const int j0 = blockIdx.x * 128 + (wave & 1) * 64;
    const float cc = params[0];

    float xsv[4][4];
#pragma unroll
    for (int r = 0; r < 4; ++r)
#pragma unroll
        for (int q = 0; q < 4; ++q) xsv[r][q] = x_sq[i0 + r * 16 + rb + q];
    float ysv[4];
#pragma unroll
    for (int c = 0; c < 4; ++c) ysv[c] = y_sq[j0 + c * 16 + fr];

    compute_tile<true>(Xh, Xl, Yh, Yl, i0, j0, la, [&](f32x4 (&acc)[4][4]) {
        float* Tw = &T[wave][0][0];
        // scatter into LDS: T[row_local][col_local]; 2-way bank aliasing only (free)
#pragma unroll
        for (int r = 0; r < 4; ++r)
#pragma unroll
            for (int c = 0; c < 4; ++c)
#pragma unroll
                for (int q = 0; q < 4; ++q) {
                    float dv = fmaf(-2.f, acc[r][c][q], xsv[r][q] + ysv[c]);
                    Tw[(r * 16 + rb + q) * 68 + c * 16 + fr] = __builtin_amdgcn_exp2f(cc * dv);
                }
        // read rows back, store 256B-contiguous per row (full lines), nontemporal
#pragma unroll
        for (int ii = 0; ii < 16; ++ii) {
            int row = ii * 4 + (lane >> 4);
            f32x4 v = *(const f32x4*)&Tw[row * 68 + fr * 4];
            f32x4* po = (f32x4*)(out + (size_t)(i0 + row) * NROWS + j0 + fr * 4);
            __builtin_nontemporal_store(v, po);
        }
    });
}

extern "C" void kernel_launch(void* const* d_in, const int* in_sizes, int n_in,
                              void* d_out, int out_size, void* d_ws, size_t ws_size,
                              hipStream_t stream) {
    const float* X = (const float*)d_in[0];
    const float* Y = (const float*)d_in[1];
    float* out = (float*)d_out;

    unsigned* hist     = (unsigned*)d_ws;
    float* x_sq        = (float*)((char*)d_ws + 8192);
    float* y_sq        = (float*)((char*)d_ws + 24576);
    float* params      = (float*)((char*)d_ws + 40960);
    unsigned* done     = (unsigned*)((char*)d_ws + 40968);
    unsigned short* Xh = (unsigned short*)((char*)d_ws + 65536);
    unsigned short* Xl = Xh + (size_t)NROWS * DDIM;
    unsigned short* Yh = Xl + (size_t)NROWS * DDIM;
    unsigned short* Yl = Yh + (size_t)NROWS * DDIM;
    unsigned* partial  = (unsigned*)((char*)d_ws + 2359296);   // 1 MB used

    prep_kernel<<<256, 256, 0, stream>>>(X, Y, Xh, Xl, Yh, Yl, x_sq, y_sq, hist, done);
    hist_kernel<<<dim3(4, 32), 256, 0, stream>>>(Xh, Xl, Yh, Yl, x_sq, y_sq, partial);
    reduce_scan_kernel<<<64, 256, 0, stream>>>(partial, hist, done, params);
    write_kernel<<<dim3(32, 32), 256, 0, stream>>>(Xh, Xl, Yh, Yl, x_sq, y_sq, params, out);
}